// Round 10
// baseline (272.193 us; speedup 1.0000x reference)
//
#include <hip/hip_runtime.h>

// VectorQuantizer MI355X (gfx950) — round 10
// R9 post-mortem: NTILE=8 spilled (VGPR capped 128, +43MB scratch traffic) -> 161us.
// This round: back to 64 vectors/wave, but 32x32x16 MFMA shape:
//   - half the MFMA instruction count (32k FLOP/instr)
//   - codebook fragments hold -2*e (hi/lo bf16 split) -> acc = cnorm_init + (-2e).x
//     = dist directly (no epilogue fma, no acc zero-init movs; cnorm float4 loads
//     ARE the accumulator init)
//   - C layout (verified m74/m101): col=lane&31, row=(r&3)+8*(r>>2)+4*(lane>>5)
//   - A/B layout: [m=lane&31][k=(lane>>5)*8+j] (x2-K analogy, verified for 16x16)
// Numerics: 3-term bf16 split, TIE_TH=1e-3 fp64 whole-wave rescan (unchanged).

#define NVEC 262144
#define DDIM 64
#define KCB  512
#define TIE_TH 1e-3f
#define NBLOCKS (NVEC / 256)             // 1024 blocks, 4 waves x 64 vectors

// ws layout (4-byte units)
#define WS_LOSS  0
#define WS_COUNT 1
#define WS_CNORM 64                      // 512 floats
#define WS_ET    1024                    // 512*64 floats (code-major codebook)
#define WS_EH    (WS_ET + KCB * DDIM)    // 64 chunk-frags * 64 lanes * uint4 = 4096
#define WS_EL    (WS_EH + 64 * 64 * 4)
#define WS_END   (WS_EL + 64 * 64 * 4)

typedef __attribute__((ext_vector_type(8)))  short bf16x8;
typedef __attribute__((ext_vector_type(16))) float f32x16;

static __device__ __forceinline__ unsigned short f2bf_rne(float f) {
    unsigned u = __float_as_uint(f);
    unsigned r = (u + 0x7FFFu + ((u >> 16) & 1u)) >> 16;
    return (unsigned short)r;
}
static __device__ __forceinline__ float bf2f(unsigned short h) {
    return __uint_as_float(((unsigned)h) << 16);
}

// ---------------- merged prep: 9 blocks x 512 ----------------
// blocks 0..7: A-fragments of (-2*codebook), 32x32x16 layout, hi/lo split.
//   frag id f = T*4 + c (T=code-tile of 32, c=k-chunk of 16), lane l:
//   elem j = -2*emb[(c*16 + (l>>5)*8 + j)*512 + T*32 + (l&31)]
// block 8: et (code-major fp32), cnorm, zero loss+counter.
__global__ __launch_bounds__(512) void vq_prep(const float* __restrict__ emb,
                                               float* __restrict__ wsf) {
    if (blockIdx.x == 8) {
        int k = threadIdx.x;
        float s = 0.f;
        float* et = wsf + WS_ET;
        #pragma unroll
        for (int d = 0; d < DDIM; ++d) {
            float e = emb[d * KCB + k];
            s += e * e;
            et[k * DDIM + d] = e;
        }
        wsf[WS_CNORM + k] = s;
        if (k == 0) {
            wsf[WS_LOSS] = 0.f;
            ((unsigned*)wsf)[WS_COUNT] = 0u;
        }
        return;
    }
    int tid = blockIdx.x * 512 + threadIdx.x;   // 0..4095
    int l  = tid & 63;
    int c  = (tid >> 6) & 3;
    int T  = tid >> 8;                           // 0..15
    int m  = T * 32 + (l & 31);
    int kb = c * 16 + (l >> 5) * 8;
    unsigned hh[4], ll[4];
    #pragma unroll
    for (int j2 = 0; j2 < 4; ++j2) {
        float f0 = -2.f * emb[(kb + 2 * j2 + 0) * KCB + m];
        float f1 = -2.f * emb[(kb + 2 * j2 + 1) * KCB + m];
        unsigned short h0 = f2bf_rne(f0), h1 = f2bf_rne(f1);
        unsigned short l0 = f2bf_rne(f0 - bf2f(h0)), l1 = f2bf_rne(f1 - bf2f(h1));
        hh[j2] = (unsigned)h0 | ((unsigned)h1 << 16);
        ll[j2] = (unsigned)l0 | ((unsigned)l1 << 16);
    }
    uint4* ehp = (uint4*)(wsf + WS_EH);
    uint4* elp = (uint4*)(wsf + WS_EL);
    ehp[tid] = make_uint4(hh[0], hh[1], hh[2], hh[3]);
    elp[tid] = make_uint4(ll[0], ll[1], ll[2], ll[3]);
}

// ---------------- main: one wave = 64 vectors (2 groups of 32) vs 512 codes ----------------
__global__ __launch_bounds__(256) void vq_main_mfma(const float* __restrict__ x,
                                                    float* __restrict__ wsf,
                                                    float* __restrict__ out) {
    const int lane = threadIdx.x & 63;
    const int nn   = lane & 31;
    const int lh   = lane >> 5;                  // k-half / row-half selector
    const int nbase = (blockIdx.x * 4 + (threadIdx.x >> 6)) * 64;

    const float* __restrict__ cnorm = wsf + WS_CNORM;
    const float* __restrict__ et    = wsf + WS_ET;
    const bf16x8* __restrict__ ehp  = (const bf16x8*)(wsf + WS_EH);
    const bf16x8* __restrict__ elp  = (const bf16x8*)(wsf + WS_EL);
    float* loss_accum = wsf + WS_LOSS;
    unsigned* counter = (unsigned*)wsf + WS_COUNT;

    // ---- x B-fragments (hi/lo) + ||x||^2 per group ----
    // B[n = lane&31][k = lh*8 + j] per chunk c (k-chunk of 16)
    bf16x8 xh[2][4], xl[2][4];
    float xnorm[2];
    #pragma unroll
    for (int g = 0; g < 2; ++g) {
        float s = 0.f;
        #pragma unroll
        for (int c = 0; c < 4; ++c) {
            const float* xrow = x + (size_t)(nbase + g * 32 + nn) * DDIM
                                  + c * 16 + lh * 8;
            float4 xa = *(const float4*)xrow;
            float4 xb = *(const float4*)(xrow + 4);
            s += xa.x * xa.x + xa.y * xa.y + xa.z * xa.z + xa.w * xa.w;
            s += xb.x * xb.x + xb.y * xb.y + xb.z * xb.z + xb.w * xb.w;
            float f[8] = {xa.x, xa.y, xa.z, xa.w, xb.x, xb.y, xb.z, xb.w};
            union { bf16x8 v; unsigned short u[8]; } H, L;
            #pragma unroll
            for (int e = 0; e < 8; ++e) {
                unsigned short h = f2bf_rne(f[e]);
                H.u[e] = h;
                L.u[e] = f2bf_rne(f[e] - bf2f(h));
            }
            xh[g][c] = H.v;
            xl[g][c] = L.v;
        }
        s += __shfl_xor(s, 32);   // other k-half holds the other 32 dims
        xnorm[g] = s;
    }

    // ---- argmin over 16 code-tiles of 32 ----
    float best[2]   = {3.4e38f, 3.4e38f};
    float second[2] = {3.4e38f, 3.4e38f};
    int   bestk[2]  = {0, 0};

    for (int T = 0; T < 16; ++T) {
        bf16x8 eh[4], el[4];
        #pragma unroll
        for (int c = 0; c < 4; ++c) {
            eh[c] = ehp[(T * 4 + c) * 64 + lane];
            el[c] = elp[(T * 4 + c) * 64 + lane];
        }
        union { float4 v4[4]; float f[16]; } cn;
        #pragma unroll
        for (int q = 0; q < 4; ++q)
            cn.v4[q] = *(const float4*)(cnorm + T * 32 + 8 * q + 4 * lh);

        const int codebase = T * 32 + 4 * lh;
        #pragma unroll
        for (int g = 0; g < 2; ++g) {
            f32x16 acc;
            #pragma unroll
            for (int r = 0; r < 16; ++r) acc[r] = cn.f[r];  // acc init = ||e||^2
            #pragma unroll
            for (int c = 0; c < 4; ++c)
                acc = __builtin_amdgcn_mfma_f32_32x32x16_bf16(eh[c], xh[g][c], acc, 0, 0, 0);
            #pragma unroll
            for (int c = 0; c < 4; ++c)
                acc = __builtin_amdgcn_mfma_f32_32x32x16_bf16(el[c], xh[g][c], acc, 0, 0, 0);
            #pragma unroll
            for (int c = 0; c < 4; ++c)
                acc = __builtin_amdgcn_mfma_f32_32x32x16_bf16(eh[c], xl[g][c], acc, 0, 0, 0);
            // acc[r] = ||e||^2 - 2 x.e  (the -2 is baked into eh/el)
            #pragma unroll
            for (int r = 0; r < 16; ++r) {
                float dist = acc[r];
                int code = codebase + (r & 3) + 8 * (r >> 2);
                bool lt = dist < best[g];
                second[g] = fminf(second[g], fmaxf(dist, best[g]));
                bestk[g] = lt ? code : bestk[g];
                best[g] = fminf(best[g], dist);
            }
        }
    }

    // ---- merge the two row-halves (lanes L and L^32) ----
    #pragma unroll
    for (int g = 0; g < 2; ++g) {
        float ob = __shfl_xor(best[g], 32);
        float os = __shfl_xor(second[g], 32);
        int   ok = __shfl_xor(bestk[g], 32);
        float ns = fminf(fminf(second[g], os), fmaxf(best[g], ob));
        bool take = (ob < best[g]) || (ob == best[g] && ok < bestk[g]);
        bestk[g] = take ? ok : bestk[g];
        best[g] = fminf(best[g], ob);
        second[g] = ns;
    }

    // ---- near-tie: whole-wave cooperative exact fp64 rescan (rare) ----
    #pragma unroll
    for (int g = 0; g < 2; ++g) {
        unsigned long long need = __ballot(second[g] - best[g] < TIE_TH) & 0xFFFFFFFFULL;
        while (need) {
            int nl = __ffsll(need) - 1;
            need &= need - 1;
            const float* xr = x + (size_t)(nbase + g * 32 + nl) * DDIM;
            double dmin = 1e300;
            int kmin = 0;
            #pragma unroll
            for (int i = 0; i < 8; ++i) {
                int k = lane * 8 + i;
                const float* er = et + k * DDIM;
                double s = 0.0;
                for (int d4 = 0; d4 < 16; ++d4) {
                    float4 xv = *(const float4*)(xr + d4 * 4);
                    float4 ev = *(const float4*)(er + d4 * 4);
                    double a = (double)xv.x - (double)ev.x; s += a * a;
                    double b = (double)xv.y - (double)ev.y; s += b * b;
                    double c = (double)xv.z - (double)ev.z; s += c * c;
                    double e = (double)xv.w - (double)ev.w; s += e * e;
                }
                if (s < dmin) { dmin = s; kmin = k; }
            }
            #pragma unroll
            for (int m = 1; m < 64; m <<= 1) {
                double od = __shfl_xor(dmin, m);
                int   ok = __shfl_xor(kmin, m);
                if (od < dmin || (od == dmin && ok < kmin)) { dmin = od; kmin = ok; }
            }
            if ((lane & 31) == nl) {
                bestk[g] = kmin;
                best[g] = (float)dmin - xnorm[g];
            }
        }
    }

    // ---- write quantized rows: 2 lanes per row, 32 floats each ----
    #pragma unroll
    for (int g = 0; g < 2; ++g) {
        int bkn = __shfl(bestk[g], lane >> 1);
        const float4* er = (const float4*)(et + (size_t)bkn * DDIM + (lane & 1) * 32);
        float4* op = (float4*)(out + (size_t)(nbase + g * 32 + (lane >> 1)) * DDIM
                                   + (lane & 1) * 32);
        #pragma unroll
        for (int i = 0; i < 8; ++i) op[i] = er[i];
    }

    // ---- loss partial + completion-counter finalize (validated R3/R9) ----
    float ls = 0.f;
    if (lane < 32) {
        #pragma unroll
        for (int g = 0; g < 2; ++g) ls += fmaxf(xnorm[g] + best[g], 0.f);
    }
    #pragma unroll
    for (int m = 1; m < 64; m <<= 1) ls += __shfl_xor(ls, m);
    if (lane == 0) atomicAdd(loss_accum, ls);

    __syncthreads();
    if (threadIdx.x == 0) {
        __threadfence();
        unsigned old = atomicAdd(counter, 1u);
        if (old == NBLOCKS - 1) {
            __threadfence();
            float total = atomicAdd(loss_accum, 0.f);
            out[(size_t)NVEC * DDIM] = 1.25f * total / 16777216.f;
        }
    }
}

// ---------------- legacy fallback if ws too small ----------------
__global__ __launch_bounds__(512) void vq_prep1_legacy(const float* __restrict__ emb,
                                                       float* __restrict__ wsf) {
    int k = threadIdx.x;
    float s = 0.f;
    float* et = wsf + WS_ET;
    #pragma unroll
    for (int d = 0; d < DDIM; ++d) {
        float e = emb[d * KCB + k];
        s += e * e;
        et[k * DDIM + d] = e;
    }
    wsf[WS_CNORM + k] = s;
    if (k == 0) wsf[WS_LOSS] = 0.f;
}

__global__ __launch_bounds__(256) void vq_main_legacy(const float* __restrict__ x,
                                                      const float* __restrict__ wsf,
                                                      float* __restrict__ out,
                                                      float* __restrict__ loss_accum) {
    const int n = blockIdx.x * 256 + threadIdx.x;
    const float* __restrict__ cnorm = wsf + WS_CNORM;
    const float* __restrict__ et    = wsf + WS_ET;
    float xr[DDIM];
    {
        const float4* xp = (const float4*)(x + (size_t)n * DDIM);
        #pragma unroll
        for (int d4 = 0; d4 < DDIM / 4; ++d4) {
            float4 v = xp[d4];
            xr[4 * d4 + 0] = v.x; xr[4 * d4 + 1] = v.y;
            xr[4 * d4 + 2] = v.z; xr[4 * d4 + 3] = v.w;
        }
    }
    float best = 3.4e38f, second = 3.4e38f;
    int bestk = 0;
    for (int k0 = 0; k0 < KCB; k0 += 8) {
        float acc[8];
        #pragma unroll
        for (int j = 0; j < 8; ++j) {
            const float* ek = et + (k0 + j) * DDIM;
            float s = 0.f;
            #pragma unroll
            for (int d = 0; d < DDIM; ++d) s += xr[d] * ek[d];
            acc[j] = s;
        }
        #pragma unroll
        for (int j = 0; j < 8; ++j) {
            float dist = cnorm[k0 + j] - 2.f * acc[j];
            if (dist < best) { second = best; best = dist; bestk = k0 + j; }
            else if (dist < second) { second = dist; }
        }
    }
    if (second - best < TIE_TH) {
        double bestd = 1e300;
        int bkk = 0;
        for (int k = 0; k < KCB; ++k) {
            const float* ek = et + k * DDIM;
            double s = 0.0;
            #pragma unroll
            for (int d = 0; d < DDIM; ++d) {
                double diff = (double)xr[d] - (double)ek[d];
                s += diff * diff;
            }
            if (s < bestd) { bestd = s; bkk = k; }
        }
        bestk = bkk;
    }
    float sq = 0.f;
    {
        const float4* qp = (const float4*)(et + bestk * DDIM);
        float4* op = (float4*)(out + (size_t)n * DDIM);
        #pragma unroll
        for (int d4 = 0; d4 < DDIM / 4; ++d4) {
            float4 q = qp[d4];
            op[d4] = q;
            float a = q.x - xr[4 * d4 + 0];
            float b = q.y - xr[4 * d4 + 1];
            float c = q.z - xr[4 * d4 + 2];
            float e = q.w - xr[4 * d4 + 3];
            sq += a * a + b * b + c * c + e * e;
        }
    }
    #pragma unroll
    for (int off = 32; off > 0; off >>= 1) sq += __shfl_down(sq, off);
    __shared__ float red[4];
    const int lane = threadIdx.x & 63;
    const int wid  = threadIdx.x >> 6;
    if (lane == 0) red[wid] = sq;
    __syncthreads();
    if (threadIdx.x == 0) atomicAdd(loss_accum, red[0] + red[1] + red[2] + red[3]);
}

__global__ void vq_final(const float* __restrict__ loss_accum,
                         float* __restrict__ out) {
    out[(size_t)NVEC * DDIM] = 1.25f * loss_accum[0] / 16777216.f;
}

extern "C" void kernel_launch(void* const* d_in, const int* in_sizes, int n_in,
                              void* d_out, int out_size, void* d_ws, size_t ws_size,
                              hipStream_t stream) {
    const float* x   = (const float*)d_in[0];
    const float* emb = (const float*)d_in[1];
    float* out = (float*)d_out;
    float* wsf = (float*)d_ws;

    if (ws_size >= (size_t)WS_END * 4) {
        vq_prep<<<9, 512, 0, stream>>>(emb, wsf);
        vq_main_mfma<<<NBLOCKS, 256, 0, stream>>>(x, wsf, out);
    } else {
        vq_prep1_legacy<<<1, 512, 0, stream>>>(emb, wsf);
        vq_main_legacy<<<NVEC / 256, 256, 0, stream>>>(x, wsf, out, wsf + WS_LOSS);
        vq_final<<<1, 1, 0, stream>>>(wsf + WS_LOSS, out);
    }
}